// Round 4
// baseline (167.453 us; speedup 1.0000x reference)
//
#include <hip/hip_runtime.h>
#include <math.h>

#define S_ 6
#define N_ 10000
#define C_ 128
#define D_ 4
#define H_ 4
#define P_ 8
#define HF_ 28
#define WF_ 50
#define M_ (HF_ * WF_)   // 1400
#define DH_ 32
#define SM_ (S_ * M_)    // 8400
// one fp8 value-copy: S*H*M pixels x 32 B = 1,075,200 B
#define ABYTES (S_ * H_ * M_ * 32)
#define VB_SH (M_ * 32)          // 44,800 B per (s,h) plane
#define CQ 64                    // queries per attn4 block (512 thr, 8 waves)
#define NCH ((N_ + CQ - 1) / CQ) // 157

#define NB_V ((SM_ + 31) / 32)   // 263 vproj blocks
#define NB_O ((N_ + 31) / 32)    // 313 OFFL blocks

typedef float floatx2 __attribute__((ext_vector_type(2)));

// ---------------------------------------------------------------------------
// Shared GEMM body, K=128, MRx4 micro-tile, k-blocked by 4 with ds_read_b128.
//   MODE 0 (vproj): out = A@B0 + bias0 -> fp8 e4m3 (single copy).
//   MODE 1 (OFFL):  out = (A+A2)@[B0|B1] + [bias0|bias1] -> fp32 (Mrows,96).
// ---------------------------------------------------------------------------
template <int NC, int MT, int MR, int MODE>
__device__ __forceinline__ void gemm_body(
    const float* __restrict__ A, const float* __restrict__ A2,
    const float* __restrict__ B0, const float* __restrict__ B1,
    const float* __restrict__ bias0, const float* __restrict__ bias1,
    float* __restrict__ outf, char* __restrict__ out8,
    int Mrows, int m0, int tid, int nthreads, float (*Alds)[132]) {
  constexpr int NTHR = (NC / 4) * (MT / MR);

  for (int i = tid; i < MT * 32; i += nthreads) {
    int r = i >> 5, k = (i & 31) * 4;
    int row = m0 + r;
    float4 v = make_float4(0.f, 0.f, 0.f, 0.f);
    if (row < Mrows) {
      v = *(const float4*)(A + (size_t)row * C_ + k);
      if (MODE == 1) {
        float4 v2 = *(const float4*)(A2 + (size_t)row * C_ + k);
        v.x += v2.x; v.y += v2.y; v.z += v2.z; v.w += v2.w;
      }
    }
    *(float4*)(&Alds[r][k]) = v;
  }
  __syncthreads();
  if (tid >= NTHR) return;

  int ci = tid % (NC / 4);
  int mi = tid / (NC / 4);
  int c0 = ci * 4, r0 = mi * MR;

  const float* bs;
  if (MODE == 1) bs = (c0 < 64) ? bias0 + c0 : bias1 + (c0 - 64);
  else bs = bias0 + c0;

  float acc[MR][4];
#pragma unroll
  for (int j = 0; j < MR; ++j)
#pragma unroll
    for (int cc = 0; cc < 4; ++cc) acc[j][cc] = bs[cc];

#pragma unroll 2
  for (int k4 = 0; k4 < C_; k4 += 4) {
    float bf[16];
#pragma unroll
    for (int kk = 0; kk < 4; ++kk) {
      int k = k4 + kk;
      float4 b4;
      if (MODE == 1)
        b4 = (c0 < 64) ? *(const float4*)(B0 + (size_t)k * 64 + c0)
                       : *(const float4*)(B1 + (size_t)k * 32 + (c0 - 64));
      else
        b4 = *(const float4*)(B0 + (size_t)k * NC + c0);
      bf[kk * 4 + 0] = b4.x; bf[kk * 4 + 1] = b4.y;
      bf[kk * 4 + 2] = b4.z; bf[kk * 4 + 3] = b4.w;
    }
    float af[MR * 4];
#pragma unroll
    for (int j = 0; j < MR; ++j) {
      float4 a4 = *(const float4*)(&Alds[r0 + j][k4]);
      af[j * 4 + 0] = a4.x; af[j * 4 + 1] = a4.y;
      af[j * 4 + 2] = a4.z; af[j * 4 + 3] = a4.w;
    }
#pragma unroll
    for (int j = 0; j < MR; ++j)
#pragma unroll
      for (int kk = 0; kk < 4; ++kk)
#pragma unroll
        for (int cc = 0; cc < 4; ++cc)
          acc[j][cc] = fmaf(af[j * 4 + kk], bf[kk * 4 + cc], acc[j][cc]);
  }

#pragma unroll
  for (int j = 0; j < MR; ++j) {
    int row = m0 + r0 + j;
    if (row >= Mrows) continue;
    if (MODE == 0) {
      int mm = row % M_;
      int h = c0 >> 5, d0 = c0 & 31;
      int s = row / M_;
      int w = __builtin_amdgcn_cvt_pk_fp8_f32(acc[j][0], acc[j][1], 0, false);
      w = __builtin_amdgcn_cvt_pk_fp8_f32(acc[j][2], acc[j][3], w, true);
      size_t hm = (size_t)s * H_ + h;
      *(int*)(out8 + (hm * M_ + mm) * 32 + d0) = w;
    } else if (MODE == 1) {
      *(float4*)(outf + (size_t)row * 96 + c0) =
          make_float4(acc[j][0], acc[j][1], acc[j][2], acc[j][3]);
    }
  }
}

// ---------------------------------------------------------------------------
__global__ __launch_bounds__(256) void prep_kernel(
    const float* __restrict__ value, const float* __restrict__ w_val,
    const float* __restrict__ b_val, char* __restrict__ vh8,
    const float* __restrict__ query, const float* __restrict__ query_pos,
    const float* __restrict__ w_off, const float* __restrict__ b_off,
    const float* __restrict__ w_attn, const float* __restrict__ b_attn,
    float* __restrict__ OFFL) {
  __shared__ float Alds[32][132];
  int bid = blockIdx.x;
  if (bid < NB_V) {
    gemm_body<128, 32, 4, 0>(value, nullptr, w_val, nullptr, b_val, nullptr,
                             nullptr, vh8, SM_, bid * 32, threadIdx.x, 256,
                             Alds);
  } else {
    gemm_body<96, 32, 4, 1>(query, query_pos, w_off, w_attn, b_off, b_attn,
                            OFFL, nullptr, N_, (bid - NB_V) * 32, threadIdx.x,
                            256, Alds);
  }
}

// ---------------------------------------------------------------------------
// attn4: block = (h, 64-query chunk); loops s=0..5 staging V[s,h] (44.8 KB)
// into LDS, accumulating slot partials IN REGISTERS across s (no PART buffer,
// no reduce pass over HBM). Params are recomputed per role-lane (no param
// LDS table -> exactly ONE ds_read_b128 per lane-sample, vs 2 in R3).
// Softmax weights + offsets are s-invariant -> hoisted to VGPRs once.
// 512 threads = 8 waves x (8 queries x 8 roles). 2 blocks/CU.
// ---------------------------------------------------------------------------
__global__ __launch_bounds__(512, 2) void attn4_kernel(
    const float* __restrict__ OFFL,     // (N,96): [0:64)=off, [64:96)=logits
    const float* __restrict__ refpts,   // (S,1,N,D,2)
    const int*   __restrict__ bev_mask, // (S,1,N,D)
    const char*  __restrict__ wsbase,   // value fp8 at +64, (sh,M,32B)
    float* __restrict__ slot) {         // (N,128) fp32, already /cnt
  __shared__ int4 Vl4[M_ * 2];          // 44,800 B

  int bid = blockIdx.x;
  int h = bid & 3;
  int q0 = (bid >> 2) * CQ;
  int tid = threadIdx.x;
  int w = tid >> 6, lane = tid & 63;
  int qg = lane >> 3, c8 = lane & 7;
  int rowsel = (c8 >> 2) & 1, xsel = (c8 >> 1) & 1, chalf = c8 & 1;

  int q = q0 + w * 8 + qg;
  int qvalid = (q < N_);
  int qc = qvalid ? q : (N_ - 1);

  // ---- hoisted per-(q,h) params: offsets (16 f32) + softmax aw (8 f32) ----
  float off[16];
  {
    const float* ob = OFFL + (size_t)qc * 96 + h * 16;
#pragma unroll
    for (int i = 0; i < 16; i += 4) {
      float4 t = *(const float4*)(ob + i);
      off[i] = t.x; off[i + 1] = t.y; off[i + 2] = t.z; off[i + 3] = t.w;
    }
  }
  float aw[8];
  {
    const float* lg = OFFL + (size_t)qc * 96 + 64 + h * 8;
    float mx = -1e30f;
#pragma unroll
    for (int p = 0; p < 8; ++p) { aw[p] = lg[p]; mx = fmaxf(mx, aw[p]); }
    float sum = 0.f;
#pragma unroll
    for (int p = 0; p < 8; ++p) { aw[p] = expf(aw[p] - mx); sum += aw[p]; }
    float is = 1.f / sum;
#pragma unroll
    for (int p = 0; p < 8; ++p) aw[p] *= is;
  }

  floatx2 acc[8] = {{0.f, 0.f}, {0.f, 0.f}, {0.f, 0.f}, {0.f, 0.f},
                    {0.f, 0.f}, {0.f, 0.f}, {0.f, 0.f}, {0.f, 0.f}};
  int cnt = 0;

  for (int s = 0; s < S_; ++s) {
    __syncthreads();  // all waves done reading previous plane
    {
      const int4* vsrc =
          (const int4*)(wsbase + 64 + (size_t)(s * H_ + h) * VB_SH);
      for (int i = tid; i < M_ * 2; i += 512) Vl4[i] = vsrc[i];
    }
    __syncthreads();

    // per-s scalars
    const int* bm = bev_mask + ((size_t)s * N_ + qc) * D_;
    int4 bmv = *(const int4*)bm;
    int sm = (bmv.x | bmv.y | bmv.z | bmv.w) ? 1 : 0;
    cnt += sm;
    float smf = (float)sm;
    float rxy[8];
    {
      const float* rf = refpts + ((size_t)s * N_ + qc) * 8;
      float4 r0 = *(const float4*)(rf + 0);
      float4 r1 = *(const float4*)(rf + 4);
      rxy[0] = r0.x; rxy[1] = r0.y; rxy[2] = r0.z; rxy[3] = r0.w;
      rxy[4] = r1.x; rxy[5] = r1.y; rxy[6] = r1.z; rxy[7] = r1.w;
    }

#pragma unroll
    for (int p = 0; p < 8; ++p) {
      int dd = p & 3;
      float ix = rxy[dd * 2 + 0] * (float)WF_ + off[2 * p + 0] - 0.5f;
      float iy = rxy[dd * 2 + 1] * (float)HF_ + off[2 * p + 1] - 0.5f;
      float xf = floorf(ix), yf = floorf(iy);
      int x0 = (int)xf, y0 = (int)yf;
      float fx = ix - xf, fy = iy - yf;
      float wx = xsel ? fx : (1.f - fx);
      float wy = rowsel ? fy : (1.f - fy);
      int xs = x0 + xsel, ys = y0 + rowsel;
      bool ok = (xs >= 0) & (xs < WF_) & (ys >= 0) & (ys < HF_);
      float wgt = ok ? wx * wy * aw[p] * smf : 0.f;
      int xc = min(max(xs, 0), WF_ - 1);
      int yc = min(max(ys, 0), HF_ - 1);
      int vidx = (yc * WF_ + xc) * 2 + chalf;
      int4 tv = Vl4[vidx];
      floatx2 wv = {wgt, wgt};
      acc[0] += __builtin_amdgcn_cvt_pk_f32_fp8(tv.x, false) * wv;
      acc[1] += __builtin_amdgcn_cvt_pk_f32_fp8(tv.x, true)  * wv;
      acc[2] += __builtin_amdgcn_cvt_pk_f32_fp8(tv.y, false) * wv;
      acc[3] += __builtin_amdgcn_cvt_pk_f32_fp8(tv.y, true)  * wv;
      acc[4] += __builtin_amdgcn_cvt_pk_f32_fp8(tv.z, false) * wv;
      acc[5] += __builtin_amdgcn_cvt_pk_f32_fp8(tv.z, true)  * wv;
      acc[6] += __builtin_amdgcn_cvt_pk_f32_fp8(tv.w, false) * wv;
      acc[7] += __builtin_amdgcn_cvt_pk_f32_fp8(tv.w, true)  * wv;
    }
  }

  // ---- fold roles (xsel bit1, rowsel bit2), divide by cnt, write slot ----
  float av[16];
#pragma unroll
  for (int k = 0; k < 8; ++k) { av[2 * k] = acc[k][0]; av[2 * k + 1] = acc[k][1]; }
#pragma unroll
  for (int k = 0; k < 16; ++k) av[k] += __shfl_xor(av[k], 2);
#pragma unroll
  for (int k = 0; k < 16; ++k) av[k] += __shfl_xor(av[k], 4);

  float inv = 1.f / (float)(cnt > 0 ? cnt : 1);
  if (c8 < 2 && qvalid) {
    float* dst = slot + (size_t)q * C_ + h * DH_ + chalf * 16;
    *(float4*)(dst + 0)  = make_float4(av[0] * inv, av[1] * inv, av[2] * inv, av[3] * inv);
    *(float4*)(dst + 4)  = make_float4(av[4] * inv, av[5] * inv, av[6] * inv, av[7] * inv);
    *(float4*)(dst + 8)  = make_float4(av[8] * inv, av[9] * inv, av[10] * inv, av[11] * inv);
    *(float4*)(dst + 12) = make_float4(av[12] * inv, av[13] * inv, av[14] * inv, av[15] * inv);
  }
}

// ---------------------------------------------------------------------------
// outproj: out = slot@w_out + b_out + query. 32-query tile per block.
// ---------------------------------------------------------------------------
__global__ __launch_bounds__(256) void outproj_kernel(
    const float* __restrict__ slot, const float* __restrict__ query,
    const float* __restrict__ w_out, const float* __restrict__ b_out,
    float* __restrict__ out) {
  __shared__ float slds[32][132];
  int q0 = blockIdx.x * 32, tid = threadIdx.x;

  for (int i = tid; i < 32 * 32; i += 256) {
    int r = i >> 5, k = (i & 31) * 4;
    int qc = min(q0 + r, N_ - 1);
    *(float4*)(&slds[r][k]) = *(const float4*)(slot + (size_t)qc * C_ + k);
  }
  __syncthreads();

  {
    int ci = tid & 31, mi = tid >> 5;
    int c0 = ci * 4, r0 = mi * 4;
    float acc[4][4];
#pragma unroll
    for (int j = 0; j < 4; ++j) {
      int qq = min(q0 + r0 + j, N_ - 1);
      float4 qv = *(const float4*)(query + (size_t)qq * C_ + c0);
      float4 bv = *(const float4*)(b_out + c0);
      acc[j][0] = bv.x + qv.x; acc[j][1] = bv.y + qv.y;
      acc[j][2] = bv.z + qv.z; acc[j][3] = bv.w + qv.w;
    }
#pragma unroll 2
    for (int k4 = 0; k4 < C_; k4 += 4) {
      float bf[16];
#pragma unroll
      for (int kk = 0; kk < 4; ++kk) {
        float4 b4 = *(const float4*)(w_out + (size_t)(k4 + kk) * C_ + c0);
        bf[kk * 4 + 0] = b4.x; bf[kk * 4 + 1] = b4.y;
        bf[kk * 4 + 2] = b4.z; bf[kk * 4 + 3] = b4.w;
      }
      float af[16];
#pragma unroll
      for (int j = 0; j < 4; ++j) {
        float4 a4 = *(const float4*)(&slds[r0 + j][k4]);
        af[j * 4 + 0] = a4.x; af[j * 4 + 1] = a4.y;
        af[j * 4 + 2] = a4.z; af[j * 4 + 3] = a4.w;
      }
#pragma unroll
      for (int j = 0; j < 4; ++j)
#pragma unroll
        for (int kk = 0; kk < 4; ++kk)
#pragma unroll
          for (int cc = 0; cc < 4; ++cc)
            acc[j][cc] = fmaf(af[j * 4 + kk], bf[kk * 4 + cc], acc[j][cc]);
    }
#pragma unroll
    for (int j = 0; j < 4; ++j) {
      int qq = q0 + r0 + j;
      if (qq < N_)
        *(float4*)(out + (size_t)qq * C_ + c0) =
            make_float4(acc[j][0], acc[j][1], acc[j][2], acc[j][3]);
    }
  }
}

// ---------------------------------------------------------------------------
extern "C" void kernel_launch(void* const* d_in, const int* in_sizes, int n_in,
                              void* d_out, int out_size, void* d_ws, size_t ws_size,
                              hipStream_t stream) {
  const float* query     = (const float*)d_in[0];
  const float* value     = (const float*)d_in[2];
  const float* query_pos = (const float*)d_in[3];
  const float* refpts    = (const float*)d_in[4];
  const int*   bev_mask  = (const int*)d_in[5];
  const float* w_off     = (const float*)d_in[6];
  const float* b_off     = (const float*)d_in[7];
  const float* w_attn    = (const float*)d_in[8];
  const float* b_attn    = (const float*)d_in[9];
  const float* w_val     = (const float*)d_in[10];
  const float* b_val     = (const float*)d_in[11];
  const float* w_out     = (const float*)d_in[12];
  const float* b_out     = (const float*)d_in[13];

  char* ws = (char*)d_ws;
  char* vh8   = ws + 64;                                        // ABYTES
  float* OFFL = (float*)(ws + 64 + 2 * (size_t)ABYTES + 64);    // 3,840,000 B
  float* SLOT = (float*)(ws + 64 + 2 * (size_t)ABYTES + 64 +
                         (size_t)N_ * 96 * 4);                  // 5,120,000 B

  prep_kernel<<<NB_V + NB_O, 256, 0, stream>>>(
      value, w_val, b_val, vh8, query, query_pos, w_off, b_off, w_attn, b_attn,
      OFFL);
  attn4_kernel<<<NCH * H_, 512, 0, stream>>>(OFFL, refpts, bev_mask, ws, SLOT);
  outproj_kernel<<<(N_ + 31) / 32, 256, 0, stream>>>(SLOT, query, w_out, b_out,
                                                     (float*)d_out);
}

// Round 5
// 158.318 us; speedup vs baseline: 1.0577x; 1.0577x over previous
//
#include <hip/hip_runtime.h>
#include <math.h>

#define S_ 6
#define N_ 10000
#define C_ 128
#define D_ 4
#define H_ 4
#define P_ 8
#define HF_ 28
#define WF_ 50
#define M_ (HF_ * WF_)   // 1400
#define DH_ 32
#define SM_ (S_ * M_)    // 8400
// one fp8 value-copy: S*H*M pixels x 32 B = 1,075,200 B
#define ABYTES (S_ * H_ * M_ * 32)
#define VB_SH (M_ * 32)          // 44,800 B per (s,h) plane
#define CQ 64                    // queries per attn5 block (512 thr, 8 waves)
#define NCH ((N_ + CQ - 1) / CQ) // 157

#define NB_V ((SM_ + 31) / 32)   // 263 vproj blocks
#define NB_O ((N_ + 31) / 32)    // 313 OFFL blocks

typedef float floatx2 __attribute__((ext_vector_type(2)));

// ---------------------------------------------------------------------------
// Shared GEMM body, K=128, MRx4 micro-tile, k-blocked by 4 with ds_read_b128.
//   MODE 0 (vproj): out = A@B0 + bias0 -> fp8 e4m3 (single copy).
//   MODE 1 (OFFL):  out = (A+A2)@[B0|B1] + [bias0|bias1] -> fp32 (Mrows,96).
// ---------------------------------------------------------------------------
template <int NC, int MT, int MR, int MODE>
__device__ __forceinline__ void gemm_body(
    const float* __restrict__ A, const float* __restrict__ A2,
    const float* __restrict__ B0, const float* __restrict__ B1,
    const float* __restrict__ bias0, const float* __restrict__ bias1,
    float* __restrict__ outf, char* __restrict__ out8,
    int Mrows, int m0, int tid, int nthreads, float (*Alds)[132]) {
  constexpr int NTHR = (NC / 4) * (MT / MR);

  for (int i = tid; i < MT * 32; i += nthreads) {
    int r = i >> 5, k = (i & 31) * 4;
    int row = m0 + r;
    float4 v = make_float4(0.f, 0.f, 0.f, 0.f);
    if (row < Mrows) {
      v = *(const float4*)(A + (size_t)row * C_ + k);
      if (MODE == 1) {
        float4 v2 = *(const float4*)(A2 + (size_t)row * C_ + k);
        v.x += v2.x; v.y += v2.y; v.z += v2.z; v.w += v2.w;
      }
    }
    *(float4*)(&Alds[r][k]) = v;
  }
  __syncthreads();
  if (tid >= NTHR) return;

  int ci = tid % (NC / 4);
  int mi = tid / (NC / 4);
  int c0 = ci * 4, r0 = mi * MR;

  const float* bs;
  if (MODE == 1) bs = (c0 < 64) ? bias0 + c0 : bias1 + (c0 - 64);
  else bs = bias0 + c0;

  float acc[MR][4];
#pragma unroll
  for (int j = 0; j < MR; ++j)
#pragma unroll
    for (int cc = 0; cc < 4; ++cc) acc[j][cc] = bs[cc];

#pragma unroll 2
  for (int k4 = 0; k4 < C_; k4 += 4) {
    float bf[16];
#pragma unroll
    for (int kk = 0; kk < 4; ++kk) {
      int k = k4 + kk;
      float4 b4;
      if (MODE == 1)
        b4 = (c0 < 64) ? *(const float4*)(B0 + (size_t)k * 64 + c0)
                       : *(const float4*)(B1 + (size_t)k * 32 + (c0 - 64));
      else
        b4 = *(const float4*)(B0 + (size_t)k * NC + c0);
      bf[kk * 4 + 0] = b4.x; bf[kk * 4 + 1] = b4.y;
      bf[kk * 4 + 2] = b4.z; bf[kk * 4 + 3] = b4.w;
    }
    float af[MR * 4];
#pragma unroll
    for (int j = 0; j < MR; ++j) {
      float4 a4 = *(const float4*)(&Alds[r0 + j][k4]);
      af[j * 4 + 0] = a4.x; af[j * 4 + 1] = a4.y;
      af[j * 4 + 2] = a4.z; af[j * 4 + 3] = a4.w;
    }
#pragma unroll
    for (int j = 0; j < MR; ++j)
#pragma unroll
      for (int kk = 0; kk < 4; ++kk)
#pragma unroll
        for (int cc = 0; cc < 4; ++cc)
          acc[j][cc] = fmaf(af[j * 4 + kk], bf[kk * 4 + cc], acc[j][cc]);
  }

#pragma unroll
  for (int j = 0; j < MR; ++j) {
    int row = m0 + r0 + j;
    if (row >= Mrows) continue;
    if (MODE == 0) {
      int mm = row % M_;
      int h = c0 >> 5, d0 = c0 & 31;
      int s = row / M_;
      int w = __builtin_amdgcn_cvt_pk_fp8_f32(acc[j][0], acc[j][1], 0, false);
      w = __builtin_amdgcn_cvt_pk_fp8_f32(acc[j][2], acc[j][3], w, true);
      size_t hm = (size_t)s * H_ + h;
      *(int*)(out8 + (hm * M_ + mm) * 32 + d0) = w;
    } else if (MODE == 1) {
      *(float4*)(outf + (size_t)row * 96 + c0) =
          make_float4(acc[j][0], acc[j][1], acc[j][2], acc[j][3]);
    }
  }
}

// ---------------------------------------------------------------------------
__global__ __launch_bounds__(256) void prep_kernel(
    const float* __restrict__ value, const float* __restrict__ w_val,
    const float* __restrict__ b_val, char* __restrict__ vh8,
    const float* __restrict__ query, const float* __restrict__ query_pos,
    const float* __restrict__ w_off, const float* __restrict__ b_off,
    const float* __restrict__ w_attn, const float* __restrict__ b_attn,
    float* __restrict__ OFFL) {
  __shared__ float Alds[32][132];
  int bid = blockIdx.x;
  if (bid < NB_V) {
    gemm_body<128, 32, 4, 0>(value, nullptr, w_val, nullptr, b_val, nullptr,
                             nullptr, vh8, SM_, bid * 32, threadIdx.x, 256,
                             Alds);
  } else {
    gemm_body<96, 32, 4, 1>(query, query_pos, w_off, w_attn, b_off, b_attn,
                            OFFL, nullptr, N_, (bid - NB_V) * 32, threadIdx.x,
                            256, Alds);
  }
}

// ---------------------------------------------------------------------------
// attn5: block = (h, 64 queries), loops s=0..5.
// Per s: [issue global_load_lds of V plane] || [phase P: thread=(q,p)
// computes packed params ONCE per sample -> LDS table] -> barrier ->
// [phase G: role-lane gather; param = 1 broadcast ds_read + ~7 extract
// instrs]. Kills the 8x param-recompute redundancy that made attn4
// VALU-bound (320 -> ~100 instr/wave/s for the same 64 samples).
// ---------------------------------------------------------------------------
__global__ __launch_bounds__(512, 4) void attn5_kernel(
    const float* __restrict__ OFFL,     // (N,96): [0:64)=off, [64:96)=logits
    const float* __restrict__ refpts,   // (S,1,N,D,2)
    const int*   __restrict__ bev_mask, // (S,1,N,D)
    const char*  __restrict__ wsbase,   // value fp8 at +64, (sh,M,32B)
    float* __restrict__ slot) {         // (N,128) fp32, already /cnt
  __shared__ int4 Vl4[M_ * 2];          // 44,800 B
  __shared__ int4 Pp[CQ * 9];           // stride 9 int4 -> conflict-free; 9216 B

  int bid = blockIdx.x;
  int h = bid & 3;
  int q0 = (bid >> 2) * CQ;
  int tid = threadIdx.x;

  // phase-P identity: thread = (tq, tp) = (local query, point)
  int tp = tid & 7, tq = tid >> 3;
  int qP = q0 + tq;
  int qPc = (qP < N_) ? qP : (N_ - 1);

  // phase-G identity: wave covers 8 queries x 8 roles
  int w = tid >> 6, lane = tid & 63;
  int qg = lane >> 3, c8 = lane & 7;
  int rowsel = (c8 >> 2) & 1, xsel = (c8 >> 1) & 1, chalf = c8 & 1;
  int xsh = xsel << 4;
  int ql = w * 8 + qg;
  int qG = q0 + ql;
  int qGvalid = (qG < N_);

  // ---- hoisted (s-invariant): softmax weight aw_p and offset pair --------
  float aw_p, offx, offy;
  {
    const float* lg = OFFL + (size_t)qPc * 96 + 64 + h * 8;
    float4 l0 = *(const float4*)(lg + 0);
    float4 l1 = *(const float4*)(lg + 4);
    float e[8] = {l0.x, l0.y, l0.z, l0.w, l1.x, l1.y, l1.z, l1.w};
    float mx = -1e30f;
#pragma unroll
    for (int p = 0; p < 8; ++p) mx = fmaxf(mx, e[p]);
    float sum = 0.f;
#pragma unroll
    for (int p = 0; p < 8; ++p) { e[p] = expf(e[p] - mx); sum += e[p]; }
    aw_p = e[tp] / sum;
    int pd = tp >> 2, dd = tp & 3;
    const float* ob = OFFL + (size_t)qPc * 96 + h * 16 + pd * 8 + dd * 2;
    offx = ob[0]; offy = ob[1];
  }

  floatx2 acc[8] = {{0.f, 0.f}, {0.f, 0.f}, {0.f, 0.f}, {0.f, 0.f},
                    {0.f, 0.f}, {0.f, 0.f}, {0.f, 0.f}, {0.f, 0.f}};

  for (int s = 0; s < S_; ++s) {
    __syncthreads();  // previous iteration's readers done with Vl4/Pp

    // ---- issue async stage of V[s,h] (no VGPR round-trip) ----------------
    {
      const char* gsrc = wsbase + 64 + (size_t)(s * H_ + h) * VB_SH;
#pragma unroll
      for (int r = 0; r < 6; ++r) {
        int i = r * 512 + tid;
        if (i < M_ * 2) {
          __builtin_amdgcn_global_load_lds(
              (const __attribute__((address_space(1))) unsigned int*)(gsrc +
                                                                      i * 16),
              (__attribute__((address_space(3))) unsigned int*)&Vl4[i], 16, 0,
              0);
        }
      }
    }

    // ---- phase P: params once per (q,p), packed to 16 B ------------------
    {
      int dd = tp & 3;
      const float* rf = refpts + ((size_t)s * N_ + qPc) * 8 + dd * 2;
      float rx = rf[0], ry = rf[1];
      const int* bm = bev_mask + ((size_t)s * N_ + qPc) * D_;
      int4 bmv = *(const int4*)bm;
      float A = ((bmv.x | bmv.y | bmv.z | bmv.w) ? 1.f : 0.f) * aw_p;
      float ix = rx * (float)WF_ + offx - 0.5f;
      float iy = ry * (float)HF_ + offy - 0.5f;
      float xf = floorf(ix), yf = floorf(iy);
      int x0 = (int)xf, y0 = (int)yf;
      float fx = ix - xf, fy = iy - yf;
      float gx = 1.f - fx, gy = 1.f - fy;
      bool vx0 = (x0 >= 0) && (x0 < WF_);
      bool vx1 = (x0 >= -1) && (x0 < WF_ - 1);
      bool vy0 = (y0 >= 0) && (y0 < HF_);
      bool vy1 = (y0 >= -1) && (y0 < HF_ - 1);
      float w00 = (vx0 && vy0) ? gx * gy * A : 0.f;
      float w10 = (vx1 && vy0) ? fx * gy * A : 0.f;
      float w01 = (vx0 && vy1) ? gx * fy * A : 0.f;
      float w11 = (vx1 && vy1) ? fx * fy * A : 0.f;
      int yt = min(max(y0, 0), HF_ - 1) * WF_;
      int yb = min(max(y0 + 1, 0), HF_ - 1) * WF_;
      int xc0 = min(max(x0, 0), WF_ - 1);
      int xc1 = min(max(x0 + 1, 0), WF_ - 1);
      int4 pk;
      pk.x = ((yt + xc0) * 2) | (((yt + xc1) * 2) << 16);
      pk.y = ((yb + xc0) * 2) | (((yb + xc1) * 2) << 16);
      union { _Float16 hf[2]; int iv; } u01, u23;
      u01.hf[0] = (_Float16)w00; u01.hf[1] = (_Float16)w10;
      u23.hf[0] = (_Float16)w01; u23.hf[1] = (_Float16)w11;
      pk.z = u01.iv;
      pk.w = u23.iv;
      Pp[tq * 9 + tp] = pk;
    }
    __syncthreads();  // Pp written, vmcnt drained -> V plane resident

    // ---- phase G: gather (8 role-lanes per query) ------------------------
#pragma unroll
    for (int p = 0; p < 8; ++p) {
      int4 prm = Pp[ql * 9 + p];  // same addr across role-lanes: broadcast
      int vword = rowsel ? prm.y : prm.x;
      int vidx = (int)(((unsigned)vword >> xsh) & 0xffffu);
      int wword = rowsel ? prm.w : prm.z;
      union { unsigned short u; _Float16 hf; } cu;
      cu.u = (unsigned short)((unsigned)wword >> xsh);
      float wgt = (float)cu.hf;
      int4 tv = Vl4[vidx + chalf];
      floatx2 wv = {wgt, wgt};
      acc[0] += __builtin_amdgcn_cvt_pk_f32_fp8(tv.x, false) * wv;
      acc[1] += __builtin_amdgcn_cvt_pk_f32_fp8(tv.x, true)  * wv;
      acc[2] += __builtin_amdgcn_cvt_pk_f32_fp8(tv.y, false) * wv;
      acc[3] += __builtin_amdgcn_cvt_pk_f32_fp8(tv.y, true)  * wv;
      acc[4] += __builtin_amdgcn_cvt_pk_f32_fp8(tv.z, false) * wv;
      acc[5] += __builtin_amdgcn_cvt_pk_f32_fp8(tv.z, true)  * wv;
      acc[6] += __builtin_amdgcn_cvt_pk_f32_fp8(tv.w, false) * wv;
      acc[7] += __builtin_amdgcn_cvt_pk_f32_fp8(tv.w, true)  * wv;
    }
  }

  // ---- fold roles (xsel bit1, rowsel bit2), divide by cnt, write slot ----
  float av[16];
#pragma unroll
  for (int k = 0; k < 8; ++k) { av[2 * k] = acc[k][0]; av[2 * k + 1] = acc[k][1]; }
#pragma unroll
  for (int k = 0; k < 16; ++k) av[k] += __shfl_xor(av[k], 2);
#pragma unroll
  for (int k = 0; k < 16; ++k) av[k] += __shfl_xor(av[k], 4);

  if (c8 < 2 && qGvalid) {
    int cnt = 0;
#pragma unroll
    for (int s = 0; s < S_; ++s) {
      const int* bm = bev_mask + ((size_t)s * N_ + qG) * D_;
      int4 bmv = *(const int4*)bm;
      cnt += (bmv.x | bmv.y | bmv.z | bmv.w) ? 1 : 0;
    }
    float inv = 1.f / (float)(cnt > 0 ? cnt : 1);
    float* dst = slot + (size_t)qG * C_ + h * DH_ + chalf * 16;
    *(float4*)(dst + 0)  = make_float4(av[0] * inv, av[1] * inv, av[2] * inv, av[3] * inv);
    *(float4*)(dst + 4)  = make_float4(av[4] * inv, av[5] * inv, av[6] * inv, av[7] * inv);
    *(float4*)(dst + 8)  = make_float4(av[8] * inv, av[9] * inv, av[10] * inv, av[11] * inv);
    *(float4*)(dst + 12) = make_float4(av[12] * inv, av[13] * inv, av[14] * inv, av[15] * inv);
  }
}

// ---------------------------------------------------------------------------
// outproj: out = slot@w_out + b_out + query. 32-query tile per block.
// ---------------------------------------------------------------------------
__global__ __launch_bounds__(256) void outproj_kernel(
    const float* __restrict__ slot, const float* __restrict__ query,
    const float* __restrict__ w_out, const float* __restrict__ b_out,
    float* __restrict__ out) {
  __shared__ float slds[32][132];
  int q0 = blockIdx.x * 32, tid = threadIdx.x;

  for (int i = tid; i < 32 * 32; i += 256) {
    int r = i >> 5, k = (i & 31) * 4;
    int qc = min(q0 + r, N_ - 1);
    *(float4*)(&slds[r][k]) = *(const float4*)(slot + (size_t)qc * C_ + k);
  }
  __syncthreads();

  {
    int ci = tid & 31, mi = tid >> 5;
    int c0 = ci * 4, r0 = mi * 4;
    float acc[4][4];
#pragma unroll
    for (int j = 0; j < 4; ++j) {
      int qq = min(q0 + r0 + j, N_ - 1);
      float4 qv = *(const float4*)(query + (size_t)qq * C_ + c0);
      float4 bv = *(const float4*)(b_out + c0);
      acc[j][0] = bv.x + qv.x; acc[j][1] = bv.y + qv.y;
      acc[j][2] = bv.z + qv.z; acc[j][3] = bv.w + qv.w;
    }
#pragma unroll 2
    for (int k4 = 0; k4 < C_; k4 += 4) {
      float bf[16];
#pragma unroll
      for (int kk = 0; kk < 4; ++kk) {
        float4 b4 = *(const float4*)(w_out + (size_t)(k4 + kk) * C_ + c0);
        bf[kk * 4 + 0] = b4.x; bf[kk * 4 + 1] = b4.y;
        bf[kk * 4 + 2] = b4.z; bf[kk * 4 + 3] = b4.w;
      }
      float af[16];
#pragma unroll
      for (int j = 0; j < 4; ++j) {
        float4 a4 = *(const float4*)(&slds[r0 + j][k4]);
        af[j * 4 + 0] = a4.x; af[j * 4 + 1] = a4.y;
        af[j * 4 + 2] = a4.z; af[j * 4 + 3] = a4.w;
      }
#pragma unroll
      for (int j = 0; j < 4; ++j)
#pragma unroll
        for (int kk = 0; kk < 4; ++kk)
#pragma unroll
          for (int cc = 0; cc < 4; ++cc)
            acc[j][cc] = fmaf(af[j * 4 + kk], bf[kk * 4 + cc], acc[j][cc]);
    }
#pragma unroll
    for (int j = 0; j < 4; ++j) {
      int qq = q0 + r0 + j;
      if (qq < N_)
        *(float4*)(out + (size_t)qq * C_ + c0) =
            make_float4(acc[j][0], acc[j][1], acc[j][2], acc[j][3]);
    }
  }
}

// ---------------------------------------------------------------------------
extern "C" void kernel_launch(void* const* d_in, const int* in_sizes, int n_in,
                              void* d_out, int out_size, void* d_ws, size_t ws_size,
                              hipStream_t stream) {
  const float* query     = (const float*)d_in[0];
  const float* value     = (const float*)d_in[2];
  const float* query_pos = (const float*)d_in[3];
  const float* refpts    = (const float*)d_in[4];
  const int*   bev_mask  = (const int*)d_in[5];
  const float* w_off     = (const float*)d_in[6];
  const float* b_off     = (const float*)d_in[7];
  const float* w_attn    = (const float*)d_in[8];
  const float* b_attn    = (const float*)d_in[9];
  const float* w_val     = (const float*)d_in[10];
  const float* b_val     = (const float*)d_in[11];
  const float* w_out     = (const float*)d_in[12];
  const float* b_out     = (const float*)d_in[13];

  char* ws = (char*)d_ws;
  char* vh8   = ws + 64;                                        // ABYTES
  float* OFFL = (float*)(ws + 64 + 2 * (size_t)ABYTES + 64);    // 3,840,000 B
  float* SLOT = (float*)(ws + 64 + 2 * (size_t)ABYTES + 64 +
                         (size_t)N_ * 96 * 4);                  // 5,120,000 B

  prep_kernel<<<NB_V + NB_O, 256, 0, stream>>>(
      value, w_val, b_val, vh8, query, query_pos, w_off, b_off, w_attn, b_attn,
      OFFL);
  attn5_kernel<<<NCH * H_, 512, 0, stream>>>(OFFL, refpts, bev_mask, ws, SLOT);
  outproj_kernel<<<(N_ + 31) / 32, 256, 0, stream>>>(SLOT, query, w_out, b_out,
                                                     (float*)d_out);
}